// Round 12
// baseline (38.200 us; speedup 1.0000x reference)
//
#include <hip/hip_runtime.h>
#include <stdint.h>

#define NDIM 1024
#define BATCH 16
#define BCHUNK 8   // batches per block; grid.z = 2

typedef float fvec4 __attribute__((ext_vector_type(4)));

__device__ __forceinline__ float h2f(uint32_t bits16) {
    _Float16 h = __builtin_bit_cast(_Float16, (uint16_t)bits16);
    return (float)h;
}

// Fused spatially-varying 3x3 filter, barrier-free, depth-3 pipelined.
// Each WAVE owns 4 output rows x 64 cols x 8 batches, staging its private
// 6-row x 72-float LDS tile via global_load_lds, QUAD-buffered (27648 B/blk).
// Steady state keeps 3 stages (6 loads) + 3 output stores in flight via
// counted vmcnt(7) — never drains (R9: barrier drain; R10/R11: depth-2
// plateaued at 3.5-3.8 TB/s wall vs 6.8 fillBuffer on same chip).
// Halos via ds_bpermute shuffles + one 8-lane merged edge read per row:
// R11's 6 scalar ds_read_b32/batch were 8-way bank-conflicted (3.93M cy:
// 64-float lane stride, 288-float row stride = 0 mod 32 banks).
// K built once per pixel per block, fp16x2-packed in 18 VGPRs.
__global__ __launch_bounds__(256) void smallsm_fused(
    const float* __restrict__ image,
    const float* __restrict__ x,
    const float* __restrict__ w,
    const float* __restrict__ bias,
    float* __restrict__ out)
{
    __shared__ float Xlds[4][4][432];   // [wave][buf][108 vec4 slots] = 27648 B

    const int N = NDIM;
    const size_t NN = (size_t)N * N;
    const int tid  = threadIdx.x;
    const int wid  = tid >> 6;            // wave 0..3
    const int lane = tid & 63;
    const int tx   = lane & 15;           // 16 lanes in j (x4 px = 64 cols)
    const int g    = lane >> 4;           // row group 0..3 within wave
    const int jB   = blockIdx.x * 64;
    const int jT   = jB + tx * 4;
    const int iW   = blockIdx.y * 16 + wid * 4;   // wave's first output row
    const int iT   = iW + g;
    const int b0   = blockIdx.z * BCHUNK;

    const bool is_l = (tx == 0);
    const bool is_r = (tx == 15);

    // ---- staging source offsets: 2 global_load_lds per stage ----
    // per-row layout (18 vec4 slots = 72 floats): 0..15 interior cols,
    // 16 -> [jB-4..jB-1] (left halo value at float 67), 17 -> [jB+64..67]
    // (right halo at float 68). 6 rows x 18 = 108 slots; loads cover 128
    // lane-slots (20 dead, exec-masked).
    uint32_t soff0, soff1; bool sv0, sv1;
#pragma unroll
    for (int ii = 0; ii < 2; ++ii) {
        const int S    = ii * 64 + lane;
        const int row  = S / 18;
        const int slot = S - row * 18;
        const int colF = (slot < 16) ? slot * 4 : (slot == 16 ? -4 : 64);
        const int grow = iW - 1 + row;
        const int gcol = jB + colF;
        const bool v = (S < 108) && (grow >= 0) && (grow < N) &&
                       (gcol >= 0) && (gcol + 4 <= N);
        const uint32_t o = (uint32_t)(grow * N + gcol);
        if (ii == 0) { sv0 = v; soff0 = o; } else { sv1 = v; soff1 = o; }
    }
    // sv0/sv1 are never wave-wide false (interior slots of valid rows always
    // present), so every stage issues exactly 2 VMEM ops -> static vmcnt
    // bookkeeping below is exact.

    auto stage = [&](int b, int buf) {
        const float* xb = x + (size_t)(b0 + b) * NN;
        float* lb = &Xlds[wid][buf][0];
        if (sv0)
            __builtin_amdgcn_global_load_lds(
                (const __attribute__((address_space(1))) void*)(xb + soff0),
                (__attribute__((address_space(3))) void*)(lb), 16, 0, 0);
        if (sv1)
            __builtin_amdgcn_global_load_lds(
                (const __attribute__((address_space(1))) void*)(xb + soff1),
                (__attribute__((address_space(3))) void*)(lb + 256), 16, 0, 0);
    };

    // ---- prologue: image loads (K-build input), then stages 0,1,2 ----
    const bool hpred = (is_l && jT > 0) || (is_r && jT + 4 < N);
    const int  hoff  = is_r ? (jT + 4) : (jT - 1);
    float im_m[3][4], im_h[3];
#pragma unroll
    for (int r = 0; r < 3; ++r) {
        const int row = iT - 1 + r;
        const bool rv = (row >= 0) && (row < N);
        const float* rp = image + (size_t)row * N;
        fvec4 mv = {0.f, 0.f, 0.f, 0.f};
        if (rv) mv = *reinterpret_cast<const fvec4*>(rp + jT);
        im_h[r] = (rv && hpred) ? rp[hoff] : 0.f;
        im_m[r][0] = mv.x; im_m[r][1] = mv.y; im_m[r][2] = mv.z; im_m[r][3] = mv.w;
    }
    __builtin_amdgcn_sched_barrier(0);
    stage(0, 0);
    stage(1, 1);
    stage(2, 2);
    __builtin_amdgcn_sched_barrier(0);

    // ---- build K (fp32), pack fp16x2 -> Kp[18] (runs under stage latency) ----
    uint32_t Kp[18];
    {
        float im[3][6];
#pragma unroll
        for (int r = 0; r < 3; ++r) {
            float left  = __shfl_up(im_m[r][3], 1);
            float right = __shfl_down(im_m[r][0], 1);
            if (is_l) left  = im_h[r];
            if (is_r) right = im_h[r];
            im[r][0] = left;       im[r][1] = im_m[r][0]; im[r][2] = im_m[r][1];
            im[r][3] = im_m[r][2]; im[r][4] = im_m[r][3]; im[r][5] = right;
        }
#pragma unroll
        for (int p = 0; p < 9; ++p) {
            const float bv = bias[p];
            float a0 = bv, a1 = bv, a2 = bv, a3 = bv;
#pragma unroll
            for (int m = 0; m < 3; ++m) {
#pragma unroll
                for (int n = 0; n < 3; ++n) {
                    const float wv = w[p * 9 + m * 3 + n];
                    a0 += wv * im[m][0 + n];
                    a1 += wv * im[m][1 + n];
                    a2 += wv * im[m][2 + n];
                    a3 += wv * im[m][3 + n];
                }
            }
            const uint16_t q0 = __builtin_bit_cast(uint16_t, (_Float16)a0);
            const uint16_t q1 = __builtin_bit_cast(uint16_t, (_Float16)a1);
            const uint16_t q2 = __builtin_bit_cast(uint16_t, (_Float16)a2);
            const uint16_t q3 = __builtin_bit_cast(uint16_t, (_Float16)a3);
            Kp[2 * p]     = (uint32_t)q0 | ((uint32_t)q1 << 16);
            Kp[2 * p + 1] = (uint32_t)q2 | ((uint32_t)q3 << 16);
        }
    }

    // ---- apply batch k from buffer buf, store result ----
    // Interior halos via shuffle (ds_bpermute: conflict-free crossbar);
    // only lanes {0,15} of each group do one merged LDS edge read (<=2-way).
    auto apply = [&](int k, int buf) {
        const float* base = &Xlds[wid][buf][0];
        float a0 = 0.f, a1 = 0.f, a2 = 0.f, a3 = 0.f;
#pragma unroll
        for (int r = 0; r < 3; ++r) {
            const float* rp = base + (g + r) * 72;
            const bool rv = ((unsigned)(iT - 1 + r) < (unsigned)N);
            fvec4 m = *reinterpret_cast<const fvec4*>(rp + 4 * tx);
            float edge = 0.f;
            if (is_l || is_r) edge = rp[is_r ? 68 : 67];
            float lft = __shfl_up(m.w, 1);     // lane tx-1's last element
            float rgt = __shfl_down(m.x, 1);   // lane tx+1's first element
            if (is_l) lft = (jB == 0)       ? 0.f : edge;
            if (is_r) rgt = (jB + 64 >= N)  ? 0.f : edge;
            if (!rv) { m.x = 0.f; m.y = 0.f; m.z = 0.f; m.w = 0.f; lft = 0.f; rgt = 0.f; }
            const float wv[6] = { lft, m.x, m.y, m.z, m.w, rgt };
#pragma unroll
            for (int l = 0; l < 3; ++l) {
                const int p = 3 * r + l;
                const uint32_t u0 = Kp[2 * p], u1 = Kp[2 * p + 1];
                a0 += h2f(u0 & 0xffffu) * wv[l + 0];
                a1 += h2f(u0 >> 16)     * wv[l + 1];
                a2 += h2f(u1 & 0xffffu) * wv[l + 2];
                a3 += h2f(u1 >> 16)     * wv[l + 3];
            }
        }
        fvec4 res; res.x = a0; res.y = a1; res.z = a2; res.w = a3;
        fvec4* dst = reinterpret_cast<fvec4*>(
            out + (size_t)(b0 + k) * NN + (size_t)iT * N + jT);
        __builtin_nontemporal_store(res, dst);
    };

    // ---- barrier-free depth-3 pipeline.
    // Issue order: s0 s1 s2 |W0 s3 st0 |W1 s4 st1 |W2 s5 st2 |W3 s6 st3
    //              |W4 s7 st4 |W5 st5 |W6 st6 |W7 st7
    // Wk waits for stage(k)'s 2 loads; NIMM = #VMEM ops issued after them:
    // W0:4 W1:5 W2:6 W3:7 W4:7 W5:7 W6:5 W7:3.
#define WAITV(NIMM) do {                                              \
        asm volatile("s_waitcnt vmcnt(" #NIMM ")" ::: "memory");      \
        __builtin_amdgcn_sched_barrier(0);                            \
    } while (0)
#define STEP(K_, BUFR, BUFW, NIMM) do {                               \
        WAITV(NIMM);                                                  \
        if ((K_) + 3 < BCHUNK) stage((K_) + 3, BUFW);                 \
        __builtin_amdgcn_sched_barrier(0);                            \
        apply((K_), BUFR);                                            \
    } while (0)

    STEP(0, 0, 3, 4);
    STEP(1, 1, 0, 5);
    STEP(2, 2, 1, 6);
    STEP(3, 3, 2, 7);
    STEP(4, 0, 3, 7);
    STEP(5, 1, 0, 7);   // k+3=8: no stage; BUFW unused
    STEP(6, 2, 0, 5);
    STEP(7, 3, 0, 3);
#undef STEP
#undef WAITV
}

extern "C" void kernel_launch(void* const* d_in, const int* in_sizes, int n_in,
                              void* d_out, int out_size, void* d_ws, size_t ws_size,
                              hipStream_t stream) {
    const float* image = (const float*)d_in[0];
    const float* x     = (const float*)d_in[1];
    const float* w     = (const float*)d_in[2];
    const float* bias  = (const float*)d_in[3];
    float* outp = (float*)d_out;

    dim3 grid(NDIM / 64, NDIM / 16, BATCH / BCHUNK);
    dim3 block(256);
    hipLaunchKernelGGL(smallsm_fused, grid, block, 0, stream,
                       image, x, w, bias, outp);
}

// Round 13
// 36.947 us; speedup vs baseline: 1.0339x; 1.0339x over previous
//
#include <hip/hip_runtime.h>
#include <stdint.h>

#define NDIM 1024
#define BATCH 16

typedef float fvec4 __attribute__((ext_vector_type(4)));

__device__ __forceinline__ float h2f(uint32_t bits16) {
    _Float16 h = __builtin_bit_cast(_Float16, (uint16_t)bits16);
    return (float)h;
}

// Fused spatially-varying 3x3 filter, barrier-free.
// R13 = R10 verbatim EXCEPT plain stores instead of __builtin_nontemporal_store
// (single-variable A/B). Theory: nt bypasses L2 write-coalescing; our output
// is 4x256B segments at 4KB stride per wave-batch, and the full 4KB row is
// only assembled across 16 different blocks — nt forbids exactly that merge,
// throttling HBM write efficiency and (via in-order vmcnt retirement)
// back-pressuring the load pipeline. All R9-R12 variants pinned at 3.3-3.9
// TB/s wall vs 6.8 TB/s fillBuffer regardless of staging scheme.
__global__ __launch_bounds__(256) void smallsm_fused(
    const float* __restrict__ image,
    const float* __restrict__ x,
    const float* __restrict__ w,
    const float* __restrict__ bias,
    float* __restrict__ out)
{
    __shared__ float Xlds[4][3][512];   // [wave][buf][6*72 used + pad] = 24576 B

    const int N = NDIM;
    const size_t NN = (size_t)N * N;
    const int tid  = threadIdx.x;
    const int wid  = tid >> 6;            // wave 0..3
    const int lane = tid & 63;
    const int tx   = lane & 15;           // 16 lanes in j (x4 px = 64 cols)
    const int g    = lane >> 4;           // row group 0..3 within wave
    const int jB   = blockIdx.x * 64;
    const int jT   = jB + tx * 4;
    const int iW   = blockIdx.y * 16 + wid * 4;   // wave's first output row
    const int iT   = iW + g;

    const bool is_l = (tx == 0);
    const bool is_r = (tx == 15);

    // ---- staging source offsets: 2 global_load_lds per stage ----
    uint32_t soff0, soff1; bool sv0, sv1;
#pragma unroll
    for (int ii = 0; ii < 2; ++ii) {
        const int S    = ii * 64 + lane;
        const int row  = S / 18;
        const int slot = S - row * 18;
        const int colF = (slot < 16) ? slot * 4 : (slot == 16 ? -4 : 64);
        const int grow = iW - 1 + row;
        const int gcol = jB + colF;
        const bool v = (S < 108) && (grow >= 0) && (grow < N) &&
                       (gcol >= 0) && (gcol + 4 <= N);
        const uint32_t o = (uint32_t)(grow * N + gcol);
        if (ii == 0) { sv0 = v; soff0 = o; } else { sv1 = v; soff1 = o; }
    }

    auto stage = [&](int b, int buf) {
        const float* xb = x + (size_t)b * NN;
        float* lb = &Xlds[wid][buf][0];
        if (sv0)
            __builtin_amdgcn_global_load_lds(
                (const __attribute__((address_space(1))) void*)(xb + soff0),
                (__attribute__((address_space(3))) void*)(lb), 16, 0, 0);
        if (sv1)
            __builtin_amdgcn_global_load_lds(
                (const __attribute__((address_space(1))) void*)(xb + soff1),
                (__attribute__((address_space(3))) void*)(lb + 256), 16, 0, 0);
    };

    // ---- prologue: image loads (K-build input), then stages 0,1 ----
    const bool hpred = (is_l && jT > 0) || (is_r && jT + 4 < N);
    const int  hoff  = is_r ? (jT + 4) : (jT - 1);
    float im_m[3][4], im_h[3];
#pragma unroll
    for (int r = 0; r < 3; ++r) {
        const int row = iT - 1 + r;
        const bool rv = (row >= 0) && (row < N);
        const float* rp = image + (size_t)row * N;
        fvec4 mv = {0.f, 0.f, 0.f, 0.f};
        if (rv) mv = *reinterpret_cast<const fvec4*>(rp + jT);
        im_h[r] = (rv && hpred) ? rp[hoff] : 0.f;
        im_m[r][0] = mv.x; im_m[r][1] = mv.y; im_m[r][2] = mv.z; im_m[r][3] = mv.w;
    }
    __builtin_amdgcn_sched_barrier(0);
    stage(0, 0);
    stage(1, 1);
    __builtin_amdgcn_sched_barrier(0);

    // ---- build K (fp32), pack fp16x2 -> Kp[18] (runs under stage latency) ----
    uint32_t Kp[18];
    {
        float im[3][6];
#pragma unroll
        for (int r = 0; r < 3; ++r) {
            float left  = __shfl_up(im_m[r][3], 1);
            float right = __shfl_down(im_m[r][0], 1);
            if (is_l) left  = im_h[r];
            if (is_r) right = im_h[r];
            im[r][0] = left;       im[r][1] = im_m[r][0]; im[r][2] = im_m[r][1];
            im[r][3] = im_m[r][2]; im[r][4] = im_m[r][3]; im[r][5] = right;
        }
#pragma unroll
        for (int p = 0; p < 9; ++p) {
            const float bv = bias[p];
            float a0 = bv, a1 = bv, a2 = bv, a3 = bv;
#pragma unroll
            for (int m = 0; m < 3; ++m) {
#pragma unroll
                for (int n = 0; n < 3; ++n) {
                    const float wv = w[p * 9 + m * 3 + n];
                    a0 += wv * im[m][0 + n];
                    a1 += wv * im[m][1 + n];
                    a2 += wv * im[m][2 + n];
                    a3 += wv * im[m][3 + n];
                }
            }
            const uint16_t q0 = __builtin_bit_cast(uint16_t, (_Float16)a0);
            const uint16_t q1 = __builtin_bit_cast(uint16_t, (_Float16)a1);
            const uint16_t q2 = __builtin_bit_cast(uint16_t, (_Float16)a2);
            const uint16_t q3 = __builtin_bit_cast(uint16_t, (_Float16)a3);
            Kp[2 * p]     = (uint32_t)q0 | ((uint32_t)q1 << 16);
            Kp[2 * p + 1] = (uint32_t)q2 | ((uint32_t)q3 << 16);
        }
    }

    // ---- apply batch k from buffer buf (literal), store result ----
    auto apply = [&](int k, int buf) {
        const float* base = &Xlds[wid][buf][0];
        float a0 = 0.f, a1 = 0.f, a2 = 0.f, a3 = 0.f;
#pragma unroll
        for (int r = 0; r < 3; ++r) {
            const float* rp = base + (g + r) * 72;
            const bool rv = ((unsigned)(iT - 1 + r) < (unsigned)N);
            fvec4 m = *reinterpret_cast<const fvec4*>(rp + 4 * tx);
            float lft = is_l ? rp[67] : rp[4 * tx - 1];
            float rgt = is_r ? rp[68] : rp[4 * tx + 4];
            if (is_l && jB == 0)      lft = 0.f;
            if (is_r && jB + 64 >= N) rgt = 0.f;
            if (!rv) { m.x = 0.f; m.y = 0.f; m.z = 0.f; m.w = 0.f; lft = 0.f; rgt = 0.f; }
            const float wv[6] = { lft, m.x, m.y, m.z, m.w, rgt };
#pragma unroll
            for (int l = 0; l < 3; ++l) {
                const int p = 3 * r + l;
                const uint32_t u0 = Kp[2 * p], u1 = Kp[2 * p + 1];
                a0 += h2f(u0 & 0xffffu) * wv[l + 0];
                a1 += h2f(u0 >> 16)     * wv[l + 1];
                a2 += h2f(u1 & 0xffffu) * wv[l + 2];
                a3 += h2f(u1 >> 16)     * wv[l + 3];
            }
        }
        fvec4 res; res.x = a0; res.y = a1; res.z = a2; res.w = a3;
        fvec4* dst = reinterpret_cast<fvec4*>(
            out + (size_t)k * NN + (size_t)iT * N + jT);
        *dst = res;   // R13: plain store (was __builtin_nontemporal_store)
    };

    // ---- barrier-free 16-batch pipeline (identical to R10) ----
#define WAITV(NIMM) do {                                              \
        asm volatile("s_waitcnt vmcnt(" #NIMM ")" ::: "memory");      \
        __builtin_amdgcn_sched_barrier(0);                            \
    } while (0)
#define STEP(K_, BUFR, BUFW, NIMM) do {                               \
        WAITV(NIMM);                                                  \
        if ((K_) + 2 < BATCH) stage((K_) + 2, BUFW);                  \
        __builtin_amdgcn_sched_barrier(0);                            \
        apply((K_), BUFR);                                            \
    } while (0)

    STEP(0,  0, 2, 2);
    STEP(1,  1, 0, 3);
    STEP(2,  2, 1, 4);
    STEP(3,  0, 2, 4);
    STEP(4,  1, 0, 4);
    STEP(5,  2, 1, 4);
    STEP(6,  0, 2, 4);
    STEP(7,  1, 0, 4);
    STEP(8,  2, 1, 4);
    STEP(9,  0, 2, 4);
    STEP(10, 1, 0, 4);
    STEP(11, 2, 1, 4);
    STEP(12, 0, 2, 4);
    STEP(13, 1, 0, 4);
    STEP(14, 2, 0, 4);   // no stage(16); BUFW unused
    STEP(15, 0, 0, 2);   // no stage(17); only st13,st14 newer than s15
#undef STEP
#undef WAITV
}

extern "C" void kernel_launch(void* const* d_in, const int* in_sizes, int n_in,
                              void* d_out, int out_size, void* d_ws, size_t ws_size,
                              hipStream_t stream) {
    const float* image = (const float*)d_in[0];
    const float* x     = (const float*)d_in[1];
    const float* w     = (const float*)d_in[2];
    const float* bias  = (const float*)d_in[3];
    float* outp = (float*)d_out;

    dim3 grid(NDIM / 64, NDIM / 16, 1);
    dim3 block(256);
    hipLaunchKernelGGL(smallsm_fused, grid, block, 0, stream,
                       image, x, w, bias, outp);
}